// Round 1
// baseline (239.097 us; speedup 1.0000x reference)
//
#include <hip/hip_runtime.h>
#include <hip/hip_bf16.h>

#define S_LEN 1024
#define NB 32
#define DM 256
#define NTOK (NB * S_LEN)   // 32768

typedef __attribute__((ext_vector_type(8))) short short8;
typedef __attribute__((ext_vector_type(4))) float f32x4;

__device__ __forceinline__ float bf2f(unsigned short u) {
    return __uint_as_float(((unsigned int)u) << 16);
}
__device__ __forceinline__ unsigned short f2bf(float f) {
    unsigned int x = __float_as_uint(f);
    return (unsigned short)((x + 0x7fffu + ((x >> 16) & 1u)) >> 16);  // RNE
}
__device__ __forceinline__ void async16(const void* g, void* l) {
    __builtin_amdgcn_global_load_lds(
        (const __attribute__((address_space(1))) void*)g,
        (__attribute__((address_space(3))) void*)l, 16, 0, 0);
}

// ---- converts ----------------------------------------------------------
__global__ void convert_inputs_kernel(const float* __restrict__ in,
                                      short* __restrict__ curF,
                                      short* __restrict__ curB) {
    int idx = blockIdx.x * blockDim.x + threadIdx.x;  // 1,048,576 threads x 8 elems
    const float4* p = (const float4*)in + (size_t)idx * 2;
    float4 a = p[0], b = p[1];
    short8 v;
    v[0] = (short)f2bf(a.x); v[1] = (short)f2bf(a.y);
    v[2] = (short)f2bf(a.z); v[3] = (short)f2bf(a.w);
    v[4] = (short)f2bf(b.x); v[5] = (short)f2bf(b.y);
    v[6] = (short)f2bf(b.z); v[7] = (short)f2bf(b.w);
    ((short8*)curF)[idx] = v;
    ((short8*)curB)[idx] = v;
}

__global__ void convert_w_kernel(const float* __restrict__ WF,
                                 const float* __restrict__ WB,
                                 short* __restrict__ WbF,
                                 short* __restrict__ WbB) {
    int dir = blockIdx.y;
    const float* src = dir ? WB : WF;
    short* dst = dir ? WbB : WbF;
    int idx = blockIdx.x * blockDim.x + threadIdx.x;  // 65536 threads x 8
    const float4* p = (const float4*)src + (size_t)idx * 2;
    float4 a = p[0], b = p[1];
    short8 v;
    v[0] = (short)f2bf(a.x); v[1] = (short)f2bf(a.y);
    v[2] = (short)f2bf(a.z); v[3] = (short)f2bf(a.w);
    v[4] = (short)f2bf(b.x); v[5] = (short)f2bf(b.y);
    v[6] = (short)f2bf(b.z); v[7] = (short)f2bf(b.w);
    ((short8*)dst)[idx] = v;
}

// ---- taps: f[s] = sum_j w[j] * x[s-4+j] (fwd) / x[s+j] (bwd), edge pads ----
__global__ void taps_kernel(const short* __restrict__ curF, const short* __restrict__ curB,
                            const float* __restrict__ fpad, const float* __restrict__ bpad,
                            const float* __restrict__ fw, const float* __restrict__ bw,
                            short* __restrict__ tmpF, short* __restrict__ tmpB) {
    int dir = blockIdx.y;
    int idx = blockIdx.x * blockDim.x + threadIdx.x;  // 1,048,576 per dir
    int t = idx >> 5;
    int d0 = (idx & 31) << 3;
    int s = t & (S_LEN - 1);
    const short* cur = dir ? curB : curF;
    const float* w5 = dir ? bw : fw;
    float acc[8];
#pragma unroll
    for (int i = 0; i < 8; i++) acc[i] = 0.0f;
#pragma unroll
    for (int j = 0; j <= 4; j++) {
        float wj = w5[j];
        bool use_pad;
        const float* pf = nullptr;
        const short* ps = nullptr;
        if (dir == 0) {
            int sj = s + j - 4;
            use_pad = (sj < 0);
            if (use_pad) pf = fpad + (size_t)(s + j) * DM + d0;           // front pad, p = s+j < 4
            else         ps = cur + (size_t)(t + j - 4) * DM + d0;
        } else {
            int sj = s + j;
            use_pad = (sj >= S_LEN);
            if (use_pad) pf = bpad + (size_t)(sj - S_LEN) * DM + d0;      // back pad
            else         ps = cur + (size_t)(t + j) * DM + d0;
        }
        if (use_pad) {
            const float4* q = (const float4*)pf;
            float4 a = q[0], b = q[1];
            acc[0] += wj * a.x; acc[1] += wj * a.y; acc[2] += wj * a.z; acc[3] += wj * a.w;
            acc[4] += wj * b.x; acc[5] += wj * b.y; acc[6] += wj * b.z; acc[7] += wj * b.w;
        } else {
            short8 v = *(const short8*)ps;
#pragma unroll
            for (int i = 0; i < 8; i++) acc[i] += wj * bf2f((unsigned short)v[i]);
        }
    }
    short8 o;
#pragma unroll
    for (int i = 0; i < 8; i++) o[i] = (short)f2bf(acc[i]);
    short* tmp = dir ? tmpB : tmpF;
    *(short8*)(tmp + (size_t)t * DM + d0) = o;
}

// ---- fused highway layer: proj = x @ W^T + b; x' = g*x + (1-g)*relu(nl) ----
// block: 512 threads (8 waves), BM=64 tokens, full N=512.
// wave w owns cols {32w..32w+31} U {256+32w..256+32w+31} so (nl, gate) pair in-lane.
template <int WRITE_OUT>
__global__ void hw_kernel(const short* __restrict__ xinF, const short* __restrict__ xinB,
                          const short* __restrict__ WF_, const short* __restrict__ WB_,
                          const float* __restrict__ bF_, const float* __restrict__ bB_,
                          short* __restrict__ xoutF, short* __restrict__ xoutB,
                          float* __restrict__ outp) {
    int dir = blockIdx.y;
    const short* xin = dir ? xinB : xinF;
    const short* W = dir ? WB_ : WF_;
    const float* bias = dir ? bB_ : bF_;
    short* xout = dir ? xoutB : xoutF;
    int ch0 = dir ? 256 : 0;

    __shared__ __align__(16) short As[64 * DM];  // 32 KB, XOR-swizzled rows

    int tid = threadIdx.x;
    int wv = tid >> 6;
    int l = tid & 63;
    int t0 = blockIdx.x * 64;

    // stage A tile: linear LDS dest, pre-swizzled global source (16B chunks)
    {
        int r0 = wv * 8;
#pragma unroll
        for (int p = 0; p < 4; p++) {
            int rr = r0 + p * 2;
            int row = rr + (l >> 5);
            int c = l & 31;
            int cs = c ^ (row & 7);
            const short* g = xin + (size_t)(t0 + row) * DM + cs * 8;
            async16((const void*)g, (void*)(As + rr * DM));
        }
    }
    asm volatile("s_waitcnt vmcnt(0)" ::: "memory");
    __syncthreads();

    int cb0 = wv * 32;
    int krow = l >> 4;
    int lc = l & 15;

    f32x4 acc[4][4];
    f32x4 zero = {0.f, 0.f, 0.f, 0.f};
#pragma unroll
    for (int i = 0; i < 4; i++)
#pragma unroll
        for (int j = 0; j < 4; j++) acc[i][j] = zero;

#pragma unroll
    for (int kk = 0; kk < 8; kk++) {
        int k = kk * 32 + krow * 8;
        short8 bfr[4];
        bfr[0] = *(const short8*)(W + (size_t)(cb0 + lc) * DM + k);
        bfr[1] = *(const short8*)(W + (size_t)(cb0 + 16 + lc) * DM + k);
        bfr[2] = *(const short8*)(W + (size_t)(256 + cb0 + lc) * DM + k);
        bfr[3] = *(const short8*)(W + (size_t)(256 + cb0 + 16 + lc) * DM + k);
        short8 afr[4];
#pragma unroll
        for (int mf = 0; mf < 4; mf++) {
            int row = mf * 16 + lc;
            int byte = (row * 512 + k * 2) ^ ((row & 7) << 4);
            afr[mf] = *(const short8*)((const char*)As + byte);
        }
#pragma unroll
        for (int mf = 0; mf < 4; mf++)
#pragma unroll
            for (int nf = 0; nf < 4; nf++)
                acc[mf][nf] = __builtin_amdgcn_mfma_f32_16x16x32_bf16(
                    afr[mf], bfr[nf], acc[mf][nf], 0, 0, 0);
    }

    // epilogue: C row = (lane>>4)*4 + reg, col = lane&15  [m89 verified mapping]
#pragma unroll
    for (int mf = 0; mf < 4; mf++) {
#pragma unroll
        for (int nfp = 0; nfp < 2; nfp++) {
            int e = cb0 + nfp * 16 + lc;
            float be = bias[e];
            float bg = bias[e + 256];
            f32x4 nl = acc[mf][nfp];
            f32x4 gt = acc[mf][nfp + 2];
#pragma unroll
            for (int r = 0; r < 4; r++) {
                int trow = mf * 16 + krow * 4 + r;
                int byte = (trow * 512 + e * 2) ^ ((trow & 7) << 4);
                float xe = bf2f(*(const unsigned short*)((const char*)As + byte));
                float nlv = nl[r] + be;
                float gv = gt[r] + bg;
                float g = 1.0f / (1.0f + __expf(-gv));
                float y = g * xe + (1.0f - g) * fmaxf(nlv, 0.0f);
                size_t t = (size_t)(t0 + trow);
                xout[t * DM + e] = (short)f2bf(y);
                if (WRITE_OUT) outp[t * 512 + ch0 + e] = y;
            }
        }
    }
}

extern "C" void kernel_launch(void* const* d_in, const int* in_sizes, int n_in,
                              void* d_out, int out_size, void* d_ws, size_t ws_size,
                              hipStream_t stream) {
    const float* inputs = (const float*)d_in[0];
    const float* fwd_pad = (const float*)d_in[1];
    const float* bwd_pad = (const float*)d_in[2];
    const float* fwd_w = (const float*)d_in[3];
    const float* bwd_w = (const float*)d_in[4];
    const float* fwd_hw_W = (const float*)d_in[5];
    const float* fwd_hw_b = (const float*)d_in[6];
    const float* bwd_hw_W = (const float*)d_in[7];
    const float* bwd_hw_b = (const float*)d_in[8];
    float* out = (float*)d_out;

    const size_t XN = (size_t)NTOK * DM;   // 8,388,608 elems
    const size_t WN = (size_t)2 * 2 * 512 * 256;  // 524,288 elems per dir
    short* curF = (short*)d_ws;
    short* curB = curF + XN;
    short* tmpF = curB + XN;
    short* tmpB = tmpF + XN;
    short* WbF = tmpB + XN;
    short* WbB = WbF + WN;   // total ws use: 4*16MB + 2*1MB = 69 MB

    convert_inputs_kernel<<<dim3(4096), dim3(256), 0, stream>>>(inputs, curF, curB);
    convert_w_kernel<<<dim3(256, 2), dim3(256), 0, stream>>>(fwd_hw_W, bwd_hw_W, WbF, WbB);

    for (int layer = 0; layer < 2; layer++) {
        const float* fpad = fwd_pad + (size_t)layer * 4 * DM;
        const float* bpad = bwd_pad + (size_t)layer * 4 * DM;
        taps_kernel<<<dim3(4096, 2), dim3(256), 0, stream>>>(
            curF, curB, fpad, bpad, fwd_w + layer * 5, bwd_w + layer * 5, tmpF, tmpB);

        const short* W0F = WbF + (size_t)(layer * 2 + 0) * 512 * 256;
        const short* W0B = WbB + (size_t)(layer * 2 + 0) * 512 * 256;
        const float* b0F = fwd_hw_b + (size_t)(layer * 2 + 0) * 512;
        const float* b0B = bwd_hw_b + (size_t)(layer * 2 + 0) * 512;
        hw_kernel<0><<<dim3(512, 2), dim3(512), 0, stream>>>(
            tmpF, tmpB, W0F, W0B, b0F, b0B, tmpF, tmpB, nullptr);  // in-place

        const short* W1F = WbF + (size_t)(layer * 2 + 1) * 512 * 256;
        const short* W1B = WbB + (size_t)(layer * 2 + 1) * 512 * 256;
        const float* b1F = fwd_hw_b + (size_t)(layer * 2 + 1) * 512;
        const float* b1B = bwd_hw_b + (size_t)(layer * 2 + 1) * 512;
        float* outl = out + (size_t)layer * NTOK * 512;
        hw_kernel<1><<<dim3(512, 2), dim3(512), 0, stream>>>(
            tmpF, tmpB, W1F, W1B, b1F, b1B, curF, curB, outl);
    }
}

// Round 3
// 210.251 us; speedup vs baseline: 1.1372x; 1.1372x over previous
//
#include <hip/hip_runtime.h>
#include <hip/hip_bf16.h>

#define S_LEN 1024
#define DM 256
#define NTOK 32768

typedef __attribute__((ext_vector_type(8))) short short8;
typedef __attribute__((ext_vector_type(4))) float f32x4;

__device__ __forceinline__ float bf2f(unsigned short u) {
    return __uint_as_float(((unsigned int)u) << 16);
}
__device__ __forceinline__ unsigned short f2bf(float f) {
    unsigned int x = __float_as_uint(f);
    return (unsigned short)((x + 0x7fffu + ((x >> 16) & 1u)) >> 16);  // RNE
}

// ---- bf16 weight convert (1 MB/dir x 2 layers) -------------------------
__global__ void convert_w_kernel(const float* __restrict__ WF,
                                 const float* __restrict__ WB,
                                 short* __restrict__ WbF,
                                 short* __restrict__ WbB) {
    int dir = blockIdx.y;
    const float* src = dir ? WB : WF;
    short* dst = dir ? WbB : WbF;
    int idx = blockIdx.x * blockDim.x + threadIdx.x;  // 65536 threads x 8
    const float4* p = (const float4*)src + (size_t)idx * 2;
    float4 a = p[0], b = p[1];
    short8 v;
    v[0] = (short)f2bf(a.x); v[1] = (short)f2bf(a.y);
    v[2] = (short)f2bf(a.z); v[3] = (short)f2bf(a.w);
    v[4] = (short)f2bf(b.x); v[5] = (short)f2bf(b.y);
    v[6] = (short)f2bf(b.z); v[7] = (short)f2bf(b.w);
    ((short8*)dst)[idx] = v;
}

// ---- GEMM: 64x512x256, A from swizzled LDS tile, W [512][256] from L2 ----
__device__ __forceinline__ void gemm_tile(const short* Alds, const short* __restrict__ W,
                                          f32x4 acc[4][4], int wv, int l) {
    int cb0 = wv * 32;
    int krow = l >> 4;
    int lc = l & 15;
#pragma unroll
    for (int kk = 0; kk < 8; kk++) {
        int k = kk * 32 + krow * 8;
        short8 bfr[4];
        bfr[0] = *(const short8*)(W + (size_t)(cb0 + lc) * DM + k);
        bfr[1] = *(const short8*)(W + (size_t)(cb0 + 16 + lc) * DM + k);
        bfr[2] = *(const short8*)(W + (size_t)(256 + cb0 + lc) * DM + k);
        bfr[3] = *(const short8*)(W + (size_t)(256 + cb0 + 16 + lc) * DM + k);
        short8 afr[4];
#pragma unroll
        for (int mf = 0; mf < 4; mf++) {
            int row = mf * 16 + lc;
            int sidx = row * DM + (((k >> 3) ^ (row & 7)) << 3);  // k&7==0
            afr[mf] = *(const short8*)(Alds + sidx);
        }
#pragma unroll
        for (int mf = 0; mf < 4; mf++)
#pragma unroll
            for (int nf = 0; nf < 4; nf++)
                acc[mf][nf] = __builtin_amdgcn_mfma_f32_16x16x32_bf16(
                    afr[mf], bfr[nf], acc[mf][nf], 0, 0, 0);
    }
}

// ---- fused per-layer kernel: taps -> hw1 -> hw2 ------------------------
// grid (512, 2): 64-token tiles x direction. 512 threads (8 waves).
template <int IN_F32, int LAST>
__global__ __launch_bounds__(512, 4)
void layer_kernel(const void* xinF_, const void* xinB_,
                  const float* __restrict__ fpad, const float* __restrict__ bpad,
                  const float* __restrict__ fw5, const float* __restrict__ bw5,
                  const short* __restrict__ WF_, const short* __restrict__ WB_,
                  const float* __restrict__ bF_, const float* __restrict__ bB_,
                  short* __restrict__ xoutF, short* __restrict__ xoutB,
                  float* __restrict__ outp) {
    int dir = blockIdx.y;
    const void* xin = dir ? xinB_ : xinF_;
    const short* W = dir ? WB_ : WF_;
    const float* bias = dir ? bB_ : bF_;
    short* xout = dir ? xoutB : xoutF;
    const float* pad = dir ? bpad : fpad;
    const float* w5g = dir ? bw5 : fw5;
    int ch0 = dir ? 256 : 0;

    __shared__ __align__(16) short As[64 * DM];  // 32 KB, XOR-swizzled (16B chunk ^ row&7)
    __shared__ __align__(16) short Bs[64 * DM];  // 32 KB

    int tid = threadIdx.x;
    int wv = tid >> 6;
    int l = tid & 63;
    int t0 = blockIdx.x * 64;

    float wj5[5];
#pragma unroll
    for (int j = 0; j < 5; j++) wj5[j] = w5g[j];

    // ---- phase 1: 5-tap conv directly into swizzled LDS tile ----
#pragma unroll
    for (int p = 0; p < 4; p++) {
        int pos = p * 512 + tid;       // 2048 (row, 16B-chunk) positions
        int row = pos >> 5;
        int c = pos & 31;
        int d0 = c << 3;
        int tg = t0 + row;
        int s = tg & (S_LEN - 1);
        float a8[8];
#pragma unroll
        for (int i = 0; i < 8; i++) a8[i] = 0.0f;
#pragma unroll
        for (int j = 0; j < 5; j++) {
            float wj = wj5[j];
            bool use_pad = (dir == 0) ? (s + j < 4) : (s + j >= S_LEN);
            if (use_pad) {
                const float* pf = (dir == 0) ? (pad + (size_t)(s + j) * DM + d0)
                                             : (pad + (size_t)(s + j - S_LEN) * DM + d0);
                const float4* q = (const float4*)pf;
                float4 a = q[0], b = q[1];
                a8[0] += wj * a.x; a8[1] += wj * a.y; a8[2] += wj * a.z; a8[3] += wj * a.w;
                a8[4] += wj * b.x; a8[5] += wj * b.y; a8[6] += wj * b.z; a8[7] += wj * b.w;
            } else {
                long st = (dir == 0) ? ((long)tg + j - 4) : ((long)tg + j);
                if (IN_F32) {
                    const float4* q = (const float4*)((const float*)xin + st * DM + d0);
                    float4 a = q[0], b = q[1];
                    a8[0] += wj * a.x; a8[1] += wj * a.y; a8[2] += wj * a.z; a8[3] += wj * a.w;
                    a8[4] += wj * b.x; a8[5] += wj * b.y; a8[6] += wj * b.z; a8[7] += wj * b.w;
                } else {
                    short8 v = *(const short8*)((const short*)xin + st * DM + d0);
#pragma unroll
                    for (int i = 0; i < 8; i++) a8[i] += wj * bf2f((unsigned short)v[i]);
                }
            }
        }
        short8 o;
#pragma unroll
        for (int i = 0; i < 8; i++) o[i] = (short)f2bf(a8[i]);
        *(short8*)(As + row * DM + ((c ^ (row & 7)) << 3)) = o;
    }
    __syncthreads();

    // ---- phase 2: highway sub-layer 0 (GEMM + gate), result -> Bs ----
    f32x4 acc[4][4];
    f32x4 zero = {0.f, 0.f, 0.f, 0.f};
#pragma unroll
    for (int i = 0; i < 4; i++)
#pragma unroll
        for (int j = 0; j < 4; j++) acc[i][j] = zero;
    gemm_tile(As, W, acc, wv, l);

    {
        int cb0 = wv * 32, krow = l >> 4, lc = l & 15;
#pragma unroll
        for (int mf = 0; mf < 4; mf++) {
#pragma unroll
            for (int nfp = 0; nfp < 2; nfp++) {
                int e = cb0 + nfp * 16 + lc;
                float be = bias[e];
                float bg = bias[e + 256];
                f32x4 nl = acc[mf][nfp];
                f32x4 gt = acc[mf][nfp + 2];
#pragma unroll
                for (int r = 0; r < 4; r++) {
                    int trow = mf * 16 + krow * 4 + r;
                    int sx = trow * DM + (((e >> 3) ^ (trow & 7)) << 3) + (e & 7);
                    float xe = bf2f((unsigned short)As[sx]);
                    float nlv = nl[r] + be;
                    float gv = gt[r] + bg;
                    float g = 1.0f / (1.0f + __expf(-gv));
                    float y = g * xe + (1.0f - g) * fmaxf(nlv, 0.0f);
                    Bs[sx] = (short)f2bf(y);  // same (trow,e) slot, swizzled
                }
            }
        }
    }
    __syncthreads();

    // ---- phase 3: highway sub-layer 1, write state + fp32 out ----
#pragma unroll
    for (int i = 0; i < 4; i++)
#pragma unroll
        for (int j = 0; j < 4; j++) acc[i][j] = zero;
    gemm_tile(Bs, W + 512 * DM, acc, wv, l);

    {
        const float* bias1 = bias + 512;
        int cb0 = wv * 32, krow = l >> 4, lc = l & 15;
#pragma unroll
        for (int mf = 0; mf < 4; mf++) {
#pragma unroll
            for (int nfp = 0; nfp < 2; nfp++) {
                int e = cb0 + nfp * 16 + lc;
                float be = bias1[e];
                float bg = bias1[e + 256];
                f32x4 nl = acc[mf][nfp];
                f32x4 gt = acc[mf][nfp + 2];
#pragma unroll
                for (int r = 0; r < 4; r++) {
                    int trow = mf * 16 + krow * 4 + r;
                    int sx = trow * DM + (((e >> 3) ^ (trow & 7)) << 3) + (e & 7);
                    float xe = bf2f((unsigned short)Bs[sx]);
                    float nlv = nl[r] + be;
                    float gv = gt[r] + bg;
                    float g = 1.0f / (1.0f + __expf(-gv));
                    float y = g * xe + (1.0f - g) * fmaxf(nlv, 0.0f);
                    size_t t = (size_t)(t0 + trow);
                    if (!LAST) xout[t * DM + e] = (short)f2bf(y);
                    outp[t * 512 + ch0 + e] = y;
                }
            }
        }
    }
}

extern "C" void kernel_launch(void* const* d_in, const int* in_sizes, int n_in,
                              void* d_out, int out_size, void* d_ws, size_t ws_size,
                              hipStream_t stream) {
    const float* inputs = (const float*)d_in[0];
    const float* fwd_pad = (const float*)d_in[1];
    const float* bwd_pad = (const float*)d_in[2];
    const float* fwd_w = (const float*)d_in[3];
    const float* bwd_w = (const float*)d_in[4];
    const float* fwd_hw_W = (const float*)d_in[5];
    const float* fwd_hw_b = (const float*)d_in[6];
    const float* bwd_hw_W = (const float*)d_in[7];
    const float* bwd_hw_b = (const float*)d_in[8];
    float* out = (float*)d_out;

    const size_t XN = (size_t)NTOK * DM;          // 8,388,608 bf16 per state buf
    const size_t WN = (size_t)2 * 2 * 512 * 256;  // per-dir bf16 weight elems
    short* curF = (short*)d_ws;
    short* curB = curF + XN;
    short* WbF = curB + XN;
    short* WbB = WbF + WN;  // total ws: 32 MB state + 4 MB weights

    convert_w_kernel<<<dim3(256, 2), dim3(256), 0, stream>>>(fwd_hw_W, bwd_hw_W, WbF, WbB);

    // layer 0: reads fp32 inputs (both dirs), writes bf16 state + fp32 out
    layer_kernel<1, 0><<<dim3(512, 2), dim3(512), 0, stream>>>(
        (const void*)inputs, (const void*)inputs,
        fwd_pad, bwd_pad, fwd_w, bwd_w,
        WbF, WbB, fwd_hw_b, bwd_hw_b,
        curF, curB, out);

    // layer 1: reads bf16 state, writes fp32 out only
    layer_kernel<0, 1><<<dim3(512, 2), dim3(512), 0, stream>>>(
        (const void*)curF, (const void*)curB,
        fwd_pad + 4 * DM, bwd_pad + 4 * DM, fwd_w + 5, bwd_w + 5,
        WbF + 2 * 512 * DM, WbB + 2 * 512 * DM,
        fwd_hw_b + 1024, bwd_hw_b + 1024,
        nullptr, nullptr, out + (size_t)NTOK * 512);
}